// Round 1
// baseline (2045.483 us; speedup 1.0000x reference)
//
#include <hip/hip_runtime.h>
#include <math.h>

#define C      128
#define KCODES 1024
#define TPB    256

// One thread per row. Row register-resident; codebook read with wave-uniform
// addresses (should scalarize to s_load); cb_sq staged in LDS per block.
// Top-2 tracking + fp64 re-decide for near-ties so argmin matches a float64
// numpy reference.
__global__ __launch_bounds__(TPB, 1)
void vq_nearest_kernel(const float* __restrict__ x,
                       const float* __restrict__ cb,
                       float* __restrict__ out_codes,
                       float* __restrict__ out_fidx,
                       float* __restrict__ out_idx,
                       float* __restrict__ out_dist,
                       int rows)
{
    __shared__ float s_cbsq[KCODES];
    const int t = threadIdx.x;

    // ---- cooperative ||c||^2 into LDS ----
    for (int k = t; k < KCODES; k += TPB) {
        const float4* cp = (const float4*)(cb + (size_t)k * C);
        float sx = 0.f, sy = 0.f, sz = 0.f, sw = 0.f;
        #pragma unroll
        for (int i = 0; i < C / 4; ++i) {
            float4 v = cp[i];
            sx += v.x * v.x; sy += v.y * v.y;
            sz += v.z * v.z; sw += v.w * v.w;
        }
        s_cbsq[k] = (sx + sy) + (sz + sw);
    }
    __syncthreads();

    const int row = blockIdx.x * TPB + t;
    if (row >= rows) return;

    // ---- load this row into registers ----
    float xr[C];
    {
        const float4* xp = (const float4*)(x + (size_t)row * C);
        #pragma unroll
        for (int i = 0; i < C / 4; ++i) {
            float4 v = xp[i];
            xr[4 * i + 0] = v.x; xr[4 * i + 1] = v.y;
            xr[4 * i + 2] = v.z; xr[4 * i + 3] = v.w;
        }
    }
    float rs;
    {
        float sx = 0.f, sy = 0.f, sz = 0.f, sw = 0.f;
        #pragma unroll
        for (int i = 0; i < C / 4; ++i) {
            sx += xr[4*i+0] * xr[4*i+0];
            sy += xr[4*i+1] * xr[4*i+1];
            sz += xr[4*i+2] * xr[4*i+2];
            sw += xr[4*i+3] * xr[4*i+3];
        }
        rs = (sx + sy) + (sz + sw);
    }

    // ---- K-loop: 4 codes per iteration, 4 independent FMA chains ----
    float v1 = INFINITY, v2 = INFINITY;
    int   k1 = 0,        k2 = 0;

    #pragma unroll 1
    for (int k0 = 0; k0 < KCODES; k0 += 4) {
        const float* c0 = cb + (size_t)k0 * C;
        float a0 = 0.f, a1 = 0.f, a2 = 0.f, a3 = 0.f;
        #pragma unroll
        for (int c = 0; c < C; ++c) {
            const float xc = xr[c];
            a0 = fmaf(xc, c0[c          ], a0);
            a1 = fmaf(xc, c0[C     + c  ], a1);
            a2 = fmaf(xc, c0[2 * C + c  ], a2);
            a3 = fmaf(xc, c0[3 * C + c  ], a3);
        }
        const float d0 = (rs + s_cbsq[k0 + 0]) - 2.f * a0;
        const float d1 = (rs + s_cbsq[k0 + 1]) - 2.f * a1;
        const float d2 = (rs + s_cbsq[k0 + 2]) - 2.f * a2;
        const float d3 = (rs + s_cbsq[k0 + 3]) - 2.f * a3;
        // strict < keeps the FIRST occurrence of the minimum (argmin semantics)
        #define UPD(dv, ki)                                             \
            if ((dv) < v1)      { v2 = v1; k2 = k1; v1 = (dv); k1 = (ki); } \
            else if ((dv) < v2) { v2 = (dv); k2 = (ki); }
        UPD(d0, k0 + 0); UPD(d1, k0 + 1); UPD(d2, k0 + 2); UPD(d3, k0 + 3);
        #undef UPD
    }

    // ---- fp64 re-decide for near-ties (rs is row-constant -> compare cq-2dot) ----
    const float EPS = 0.125f;
    if (v2 - v1 < EPS) {
        const float* c1p = cb + (size_t)k1 * C;
        const float* c2p = cb + (size_t)k2 * C;
        double dot1 = 0.0, cq1 = 0.0, dot2 = 0.0, cq2 = 0.0;
        #pragma unroll 8
        for (int c = 0; c < C; ++c) {
            const double xc  = (double)xr[c];
            const double cv1 = (double)c1p[c];
            const double cv2 = (double)c2p[c];
            dot1 += xc * cv1;  cq1 += cv1 * cv1;
            dot2 += xc * cv2;  cq2 += cv2 * cv2;
        }
        const double q1 = cq1 - 2.0 * dot1;
        const double q2 = cq2 - 2.0 * dot2;
        if (q2 < q1 || (q2 == q1 && k2 < k1)) {
            k1 = k2;
            v1 = (float)((double)rs + q2);
        }
    }

    // ---- outputs: codes gather, indices (as float), min distance ----
    {
        const float4* src = (const float4*)(cb + (size_t)k1 * C);
        float4*       dst = (float4*)(out_codes + (size_t)row * C);
        #pragma unroll
        for (int i = 0; i < C / 4; ++i) dst[i] = src[i];
        out_fidx[row] = (float)k1;
        out_idx[row]  = (float)k1;
        out_dist[row] = v1;
    }
}

extern "C" void kernel_launch(void* const* d_in, const int* in_sizes, int n_in,
                              void* d_out, int out_size, void* d_ws, size_t ws_size,
                              hipStream_t stream) {
    const float* x  = (const float*)d_in[0];
    const float* cb = (const float*)d_in[1];
    const int rows = in_sizes[0] / C;   // 65536

    float* out       = (float*)d_out;
    float* out_codes = out;                          // rows*C
    float* out_fidx  = out + (size_t)rows * C;       // rows
    float* out_idx   = out_fidx + rows;              // rows
    float* out_dist  = out_idx + rows;               // rows

    const int grid = (rows + TPB - 1) / TPB;         // 256 blocks
    vq_nearest_kernel<<<grid, TPB, 0, stream>>>(x, cb, out_codes, out_fidx,
                                                out_idx, out_dist, rows);
}